// Round 14
// baseline (425.966 us; speedup 1.0000x reference)
//
#include <hip/hip_runtime.h>
#include <hip/hip_fp16.h>
#include <hip/hip_cooperative_groups.h>
#include <math.h>

namespace cg = cooperative_groups;

#define N_NODES 50000
#define E_EDGES 1600000
#define NE_TOT  (E_EDGES + N_NODES)

// bucketed scatter geometry
#define BSH 7                                   // 128 nodes per bucket
#define NBKT ((N_NODES + 127) >> 7)             // 391 buckets
#define EPW 4096                                // edges per A-pass workgroup
#define NWA ((NE_TOT + EPW - 1) / EPW)          // 403 workgroups

#define CH 128                                  // staged edges per node chunk

// ---------------- fused: per-WG bucket histogram  ||  layer-1 GEMM ----------------

__device__ __forceinline__ void gemm_att_body(
    int bid, int t, float* Wl, float* xs,
    const float* __restrict__ X, const float* __restrict__ W,
    const float* __restrict__ attS, const float* __restrict__ attD,
    __half* __restrict__ H16, float* __restrict__ a_s, float* __restrict__ a_d) {
    int g = t >> 5, cl = t & 31, c4 = cl * 4;
    int rowbase = bid * 32;
    float4 acc[4];
    #pragma unroll
    for (int rr = 0; rr < 4; rr++) acc[rr] = make_float4(0.f, 0.f, 0.f, 0.f);

    for (int kp = 0; kp < 2; kp++) {
        __syncthreads();
        #pragma unroll
        for (int j = 0; j < 8; j++) {
            int f4 = t + 256 * j;
            int kk = f4 >> 5, cg2 = f4 & 31;
            *(float4*)&Wl[kk * 128 + cg2 * 4] =
                *(const float4*)&W[(kp * 64 + kk) * 128 + cg2 * 4];
        }
        #pragma unroll
        for (int j = 0; j < 2; j++) {
            int f4 = t + 256 * j;
            int r = f4 >> 4, k4 = f4 & 15;
            int grow = rowbase + r;
            float4 xv = make_float4(0.f, 0.f, 0.f, 0.f);
            if (grow < N_NODES) xv = *(const float4*)&X[grow * 128 + kp * 64 + k4 * 4];
            *(float4*)&xs[r * 64 + k4 * 4] = xv;
        }
        __syncthreads();
        #pragma unroll
        for (int k4 = 0; k4 < 16; k4++) {
            float4 xv[4];
            #pragma unroll
            for (int rr = 0; rr < 4; rr++)
                xv[rr] = *(float4*)&xs[(g * 4 + rr) * 64 + k4 * 4];
            #pragma unroll
            for (int kk = 0; kk < 4; kk++) {
                float4 wv = *(float4*)&Wl[(k4 * 4 + kk) * 128 + c4];
                #pragma unroll
                for (int rr = 0; rr < 4; rr++) {
                    float xc = (kk == 0) ? xv[rr].x : (kk == 1) ? xv[rr].y
                             : (kk == 2) ? xv[rr].z : xv[rr].w;
                    acc[rr].x += xc * wv.x;
                    acc[rr].y += xc * wv.y;
                    acc[rr].z += xc * wv.z;
                    acc[rr].w += xc * wv.w;
                }
            }
        }
    }

    float4 as4 = *(const float4*)&attS[c4];
    float4 ad4 = *(const float4*)&attD[c4];
    int head = cl >> 3;
    #pragma unroll
    for (int rr = 0; rr < 4; rr++) {
        int grow = rowbase + g * 4 + rr;
        float4 a = acc[rr];
        if (grow < N_NODES) {
            __half2 lo = __floats2half2_rn(a.x, a.y);
            __half2 hi = __floats2half2_rn(a.z, a.w);
            uint2 pk;
            pk.x = *(unsigned int*)&lo;
            pk.y = *(unsigned int*)&hi;
            *(uint2*)&H16[(size_t)grow * 128 + c4] = pk;
        }
        float ps = a.x * as4.x + a.y * as4.y + a.z * as4.z + a.w * as4.w;
        float pd = a.x * ad4.x + a.y * ad4.y + a.z * ad4.z + a.w * ad4.w;
        ps += __shfl_xor(ps, 1); ps += __shfl_xor(ps, 2); ps += __shfl_xor(ps, 4);
        pd += __shfl_xor(pd, 1); pd += __shfl_xor(pd, 2); pd += __shfl_xor(pd, 4);
        if ((cl & 7) == 0 && grow < N_NODES) {
            a_s[grow * 4 + head] = ps;
            a_d[grow * 4 + head] = pd;
        }
    }
}

__global__ __launch_bounds__(256) void k_hist_gemm(
    const int* __restrict__ ei, int* __restrict__ histG,
    const float* __restrict__ X, const float* __restrict__ W,
    const float* __restrict__ attS, const float* __restrict__ attD,
    __half* __restrict__ H16, float* __restrict__ a_s, float* __restrict__ a_d) {
    __shared__ __align__(16) char smem[40960];
    int t = threadIdx.x;
    if (blockIdx.x < NWA) {
        int* h = (int*)smem;
        for (int i = t; i < NBKT; i += 256) h[i] = 0;
        __syncthreads();
        int base = blockIdx.x * EPW;
        #pragma unroll 4
        for (int j = 0; j < EPW / 256; j++) {
            int e = base + t + 256 * j;
            if (e < NE_TOT) {
                int d = (e < E_EDGES) ? ei[E_EDGES + e] : (e - E_EDGES);
                atomicAdd(&h[d >> BSH], 1);
            }
        }
        __syncthreads();
        for (int i = t; i < NBKT; i += 256) histG[blockIdx.x * NBKT + i] = h[i];
    } else {
        float* Wl = (float*)smem;              // 64*128 floats = 32KB
        float* xs = (float*)(smem + 32768);    // 32*64 floats = 8KB
        gemm_att_body(blockIdx.x - NWA, t, Wl, xs, X, W, attS, attD, H16, a_s, a_d);
    }
}

// standalone GEMM (layer 2)
__global__ __launch_bounds__(256) void k_gemm_att(
    const float* __restrict__ X, const float* __restrict__ W,
    const float* __restrict__ attS, const float* __restrict__ attD,
    __half* __restrict__ H16, float* __restrict__ a_s, float* __restrict__ a_d) {
    __shared__ float Wl[64 * 128];
    __shared__ float xs[32 * 64];
    gemm_att_body(blockIdx.x, threadIdx.x, Wl, xs, X, W, attS, attD, H16, a_s, a_d);
}

// ---------------- cooperative CSR build: scan + base + scatter + sort ----------------
// One kernel, 4 phases separated by grid.sync(). 403 blocks x 256 threads
// (tiny LDS/regs -> trivially co-resident on 256 CUs).

__global__ __launch_bounds__(256) void k_csr(
    const int* __restrict__ ei, int* __restrict__ histG,
    int* __restrict__ bktTotal, int* __restrict__ bktBase,
    int* __restrict__ row_start, unsigned int* __restrict__ pairs,
    unsigned short* __restrict__ col) {
    cg::grid_group grid = cg::this_grid();
    __shared__ int smem[512];
    int t = threadIdx.x;
    int b = blockIdx.x;

    // ---- phase 1: per-bucket exclusive scan of histG over the WG axis ----
    if (b < NBKT) {
        int w0 = 2 * t, w1 = 2 * t + 1;
        int a0 = (w0 < NWA) ? histG[w0 * NBKT + b] : 0;
        int a1 = (w1 < NWA) ? histG[w1 * NBKT + b] : 0;
        smem[w0] = a0; smem[w1] = a1;
        __syncthreads();
        for (int d = 1; d < 512; d <<= 1) {
            int x0 = (w0 >= d) ? smem[w0 - d] : 0;
            int x1 = (w1 >= d) ? smem[w1 - d] : 0;
            __syncthreads();
            smem[w0] += x0; smem[w1] += x1;
            __syncthreads();
        }
        if (w0 < NWA) histG[w0 * NBKT + b] = smem[w0] - a0;   // exclusive
        if (w1 < NWA) histG[w1 * NBKT + b] = smem[w1] - a1;
        if (t == 255) bktTotal[b] = smem[511];
    }
    grid.sync();

    // ---- phase 2: block 0 scans bucket totals -> bucket bases ----
    if (b == 0) {
        int i0 = 2 * t, i1 = 2 * t + 1;
        int v0 = (i0 < NBKT) ? bktTotal[i0] : 0;
        int v1 = (i1 < NBKT) ? bktTotal[i1] : 0;
        smem[i0] = v0; smem[i1] = v1;
        __syncthreads();
        for (int d = 1; d < 512; d <<= 1) {
            int x0 = (i0 >= d) ? smem[i0 - d] : 0;
            int x1 = (i1 >= d) ? smem[i1 - d] : 0;
            __syncthreads();
            smem[i0] += x0; smem[i1] += x1;
            __syncthreads();
        }
        if (i0 < NBKT) bktBase[i0] = smem[i0] - v0;
        if (i1 < NBKT) bktBase[i1] = smem[i1] - v1;
        if (t == 255) {
            bktBase[NBKT] = smem[511];
            row_start[N_NODES] = smem[511];
        }
    }
    grid.sync();

    // ---- phase 3: scatter (src,dst) pairs into per-WG bucket streams ----
    {
        int* lofs = smem;   // NBKT <= 512
        for (int i = t; i < NBKT; i += 256)
            lofs[i] = bktBase[i] + histG[b * NBKT + i];
        __syncthreads();
        int base = b * EPW;
        #pragma unroll 4
        for (int j = 0; j < EPW / 256; j++) {
            int e = base + t + 256 * j;
            if (e < NE_TOT) {
                int s, d;
                if (e < E_EDGES) { s = ei[e]; d = ei[E_EDGES + e]; }
                else             { s = d = e - E_EDGES; }
                int pos = atomicAdd(&lofs[d >> BSH], 1);
                pairs[pos] = ((unsigned int)d << 16) | (unsigned int)s;
            }
        }
        __syncthreads();
    }
    grid.sync();

    // ---- phase 4: per-bucket node-level sort -> row_start + col ----
    if (b < NBKT) {
        int* cnt = smem;            // 128
        int* sc  = smem + 128;      // 128
        int* cur = smem + 256;      // 128
        int nbeg = b << BSH;
        int ebeg = bktBase[b], eend = bktBase[b + 1];
        if (t < (1 << BSH)) cnt[t] = 0;
        __syncthreads();
        for (int j = ebeg + t; j < eend; j += 256)
            atomicAdd(&cnt[(int)(pairs[j] >> 16) - nbeg], 1);
        __syncthreads();
        int v = (t < (1 << BSH)) ? cnt[t] : 0;
        if (t < (1 << BSH)) sc[t] = v;
        __syncthreads();
        for (int d = 1; d < (1 << BSH); d <<= 1) {
            int x = 0;
            if (t < (1 << BSH) && t >= d) x = sc[t - d];
            __syncthreads();
            if (t < (1 << BSH)) sc[t] += x;
            __syncthreads();
        }
        if (t < (1 << BSH)) {
            int pos = ebeg + sc[t] - v;      // exclusive
            cur[t] = pos;
            int node = nbeg + t;
            if (node < N_NODES) row_start[node] = pos;
        }
        __syncthreads();
        for (int j = ebeg + t; j < eend; j += 256) {
            unsigned int p = pairs[j];
            int pos = atomicAdd(&cur[(int)(p >> 16) - nbeg], 1);
            col[pos] = (unsigned short)(p & 0xFFFFu);
        }
    }
}

// ---------------- Attention aggregation ----------------

__device__ inline float sel4(float4 v, int i) {
    float r = v.x;
    if (i == 1) r = v.y;
    if (i == 2) r = v.z;
    if (i == 3) r = v.w;
    return r;
}

// p = exp(leaky_relu(a + b)) — no max subtraction (|logits| <~ 2, fp32-safe)
__device__ inline float4 expleaky4(float4 a, float4 b) {
    float4 e, p;
    e.x = a.x + b.x; e.x = e.x > 0.f ? e.x : 0.2f * e.x; p.x = __expf(e.x);
    e.y = a.y + b.y; e.y = e.y > 0.f ? e.y : 0.2f * e.y; p.y = __expf(e.y);
    e.z = a.z + b.z; e.z = e.z > 0.f ? e.z : 0.2f * e.z; p.z = __expf(e.z);
    e.w = a.w + b.w; e.w = e.w > 0.f ? e.w : 0.2f * e.w; p.w = __expf(e.w);
    return p;
}

#define ACC8(q, raw)                                              \
    do {                                                          \
        const __half2* hp_ = (const __half2*)&(raw);              \
        float2 f0_ = __half22float2(hp_[0]);                      \
        float2 f1_ = __half22float2(hp_[1]);                      \
        float2 f2_ = __half22float2(hp_[2]);                      \
        float2 f3_ = __half22float2(hp_[3]);                      \
        acc8[0] = fmaf((q), f0_.x, acc8[0]);                      \
        acc8[1] = fmaf((q), f0_.y, acc8[1]);                      \
        acc8[2] = fmaf((q), f1_.x, acc8[2]);                      \
        acc8[3] = fmaf((q), f1_.y, acc8[3]);                      \
        acc8[4] = fmaf((q), f2_.x, acc8[4]);                      \
        acc8[5] = fmaf((q), f2_.y, acc8[5]);                      \
        acc8[6] = fmaf((q), f3_.x, acc8[6]);                      \
        acc8[7] = fmaf((q), f3_.y, acc8[7]);                      \
    } while (0)

// R10-validated geometry: 256-thread blocks = 4 waves = 4 independent nodes;
// consume: 4 edge slots x 16 channel-lanes x 8 ch/lane, 4-deep load batching.
template<int MODE>   // 1: layer-1 (ELU -> Hout fp32); 0: layer-2 (fused out-proj)
__global__ __launch_bounds__(256) void k_agg(
    const __half* __restrict__ H16, const float* __restrict__ a_s,
    const float* __restrict__ a_d, const int* __restrict__ row_start,
    const unsigned short* __restrict__ col, const float* __restrict__ bias,
    float* __restrict__ Hout,
    const float* __restrict__ Wout, const float* __restrict__ bout,
    float* __restrict__ out) {
    __shared__ float4 eS[4][CH];    // staged p per wave
    __shared__ int    sS[4][CH];    // staged src per wave
    __shared__ float  WoT[(MODE == 0) ? 1024 : 1];  // transposed Wout [8][128]
    __shared__ float  boL[(MODE == 0) ? 8 : 1];

    if (MODE == 0) {
        for (int j = threadIdx.x; j < 1024; j += 256) {
            int o = j >> 7, k = j & 127;
            WoT[o * 128 + k] = Wout[k * 8 + o];
        }
        if (threadIdx.x < 8) boL[threadIdx.x] = bout[threadIdx.x];
        __syncthreads();
    }

    int wid = threadIdx.x >> 6;
    int lane = threadIdx.x & 63;
    int node = blockIdx.x * 4 + wid;
    if (node >= N_NODES) return;
    int beg = row_start[node], end = row_start[node + 1];
    int deg = end - beg;
    float4 ad4 = *(const float4*)&a_d[node * 4];
    float4* eA = eS[wid];
    int*    srcA = sS[wid];

    // single pass: p = exp(leaky(e)), stage {src,p} (first CH), accumulate denom
    float4 s = make_float4(0.f, 0.f, 0.f, 0.f);
    for (int j = beg + lane; j < end; j += 64) {
        int src = (int)col[j];
        float4 av = *(const float4*)&a_s[src * 4];
        float4 p = expleaky4(av, ad4);
        int idx = j - beg;
        if (idx < CH) { srcA[idx] = src; eA[idx] = p; }
        s.x += p.x; s.y += p.y; s.z += p.z; s.w += p.w;
    }
    #pragma unroll
    for (int off = 32; off > 0; off >>= 1) {
        s.x += __shfl_xor(s.x, off);
        s.y += __shfl_xor(s.y, off);
        s.z += __shfl_xor(s.z, off);
        s.w += __shfl_xor(s.w, off);
    }
    float4 inv;
    inv.x = 1.f / (s.x + 1e-16f);
    inv.y = 1.f / (s.y + 1e-16f);
    inv.z = 1.f / (s.z + 1e-16f);
    inv.w = 1.f / (s.w + 1e-16f);

    // consume: 4 edge slots x 16 channel-lanes (8 fp16 ch each = 16B load);
    // 4-edge batches per slot for MLP
    int eslot = lane >> 4, cl16 = lane & 15, head = cl16 >> 2;
    const __half* hbase = H16 + cl16 * 8;
    const float* pA = (const float*)eA;
    float acc8[8];
    #pragma unroll
    for (int k = 0; k < 8; k++) acc8[k] = 0.f;

    int nst = min(deg, CH);
    int i = eslot;
    for (; i + 12 < nst; i += 16) {
        int s0 = srcA[i];
        int s1 = srcA[i + 4];
        int s2 = srcA[i + 8];
        int s3 = srcA[i + 12];
        float q0 = pA[i * 4 + head];
        float q1 = pA[(i + 4) * 4 + head];
        float q2 = pA[(i + 8) * 4 + head];
        float q3 = pA[(i + 12) * 4 + head];
        float4 r0 = *(const float4*)(hbase + (size_t)s0 * 128);
        float4 r1 = *(const float4*)(hbase + (size_t)s1 * 128);
        float4 r2 = *(const float4*)(hbase + (size_t)s2 * 128);
        float4 r3 = *(const float4*)(hbase + (size_t)s3 * 128);
        ACC8(q0, r0);
        ACC8(q1, r1);
        ACC8(q2, r2);
        ACC8(q3, r3);
    }
    for (; i < nst; i += 4) {
        int src = srcA[i];
        float p = pA[i * 4 + head];
        float4 raw = *(const float4*)(hbase + (size_t)src * 128);
        ACC8(p, raw);
    }
    // overflow chunks (deg > CH, rare): restage then consume
    for (int cb = beg + CH; cb < end; cb += CH) {
        int cnt = min(end - cb, CH);
        for (int idx = lane; idx < cnt; idx += 64) {
            int src = (int)col[cb + idx];
            float4 av = *(const float4*)&a_s[src * 4];
            float4 p = expleaky4(av, ad4);
            srcA[idx] = src; eA[idx] = p;
        }
        for (int ii = eslot; ii < cnt; ii += 4) {
            int src = srcA[ii];
            float p = pA[ii * 4 + head];
            float4 raw = *(const float4*)(hbase + (size_t)src * 128);
            ACC8(p, raw);
        }
    }

    #pragma unroll
    for (int k = 0; k < 8; k++) {
        acc8[k] += __shfl_xor(acc8[k], 16);
        acc8[k] += __shfl_xor(acc8[k], 32);
    }

    float ih = sel4(inv, head);
    if (MODE == 1) {
        if (eslot == 0) {
            const float* bp = &bias[cl16 * 8];
            float o[8];
            #pragma unroll
            for (int k = 0; k < 8; k++) {
                o[k] = acc8[k] * ih + bp[k];
                o[k] = o[k] > 0.f ? o[k] : expm1f(o[k]);
            }
            float* op = &Hout[(size_t)node * 128 + cl16 * 8];
            *(float4*)&op[0] = make_float4(o[0], o[1], o[2], o[3]);
            *(float4*)&op[4] = make_float4(o[4], o[5], o[6], o[7]);
        }
    } else {
        // fused output projection: h2 = acc*ih + b2 (all lanes hold it),
        // each eslot computes 2 of the 8 outputs
        const float* bp = &bias[cl16 * 8];
        float4 oa, ob;
        oa.x = acc8[0] * ih + bp[0]; oa.y = acc8[1] * ih + bp[1];
        oa.z = acc8[2] * ih + bp[2]; oa.w = acc8[3] * ih + bp[3];
        ob.x = acc8[4] * ih + bp[4]; ob.y = acc8[5] * ih + bp[5];
        ob.z = acc8[6] * ih + bp[6]; ob.w = acc8[7] * ih + bp[7];
        int o0 = eslot * 2;
        float p0 = 0.f, p1 = 0.f;
        {
            float4 wa = *(float4*)&WoT[o0 * 128 + cl16 * 8];
            float4 wb = *(float4*)&WoT[o0 * 128 + cl16 * 8 + 4];
            p0 = oa.x * wa.x + oa.y * wa.y + oa.z * wa.z + oa.w * wa.w
               + ob.x * wb.x + ob.y * wb.y + ob.z * wb.z + ob.w * wb.w;
            float4 wc = *(float4*)&WoT[(o0 + 1) * 128 + cl16 * 8];
            float4 wd = *(float4*)&WoT[(o0 + 1) * 128 + cl16 * 8 + 4];
            p1 = oa.x * wc.x + oa.y * wc.y + oa.z * wc.z + oa.w * wc.w
               + ob.x * wd.x + ob.y * wd.y + ob.z * wd.z + ob.w * wd.w;
        }
        #pragma unroll
        for (int d = 1; d <= 8; d <<= 1) {
            p0 += __shfl_xor(p0, d);
            p1 += __shfl_xor(p1, d);
        }
        if (cl16 == 0) {
            float2 ov = make_float2(p0 + boL[o0], p1 + boL[o0 + 1]);
            *(float2*)&out[(size_t)node * 8 + o0] = ov;
        }
    }
}

// ---------------- launch ----------------

extern "C" void kernel_launch(void* const* d_in, const int* in_sizes, int n_in,
                              void* d_out, int out_size, void* d_ws, size_t ws_size,
                              hipStream_t stream) {
    const float* x     = (const float*)d_in[0];
    const int*   ei    = (const int*)d_in[1];
    const float* W1    = (const float*)d_in[2];
    const float* attS1 = (const float*)d_in[3];
    const float* attD1 = (const float*)d_in[4];
    const float* b1    = (const float*)d_in[5];
    const float* W2    = (const float*)d_in[6];
    const float* attS2 = (const float*)d_in[7];
    const float* attD2 = (const float*)d_in[8];
    const float* b2    = (const float*)d_in[9];
    const float* Wout  = (const float*)d_in[10];
    const float* bout  = (const float*)d_in[11];
    float* out = (float*)d_out;

    char* ws = (char*)d_ws;
    size_t off = 0;
    auto alloc = [&](size_t bytes) -> void* {
        void* p = ws + off;
        off += (bytes + 255) & ~(size_t)255;
        return p;
    };
    float*          hB        = (float*)alloc((size_t)N_NODES * 128 * 4);
    __half*         h16       = (__half*)alloc((size_t)N_NODES * 128 * 2);
    float*          a_s       = (float*)alloc((size_t)N_NODES * 4 * 4);
    float*          a_d       = (float*)alloc((size_t)N_NODES * 4 * 4);
    int*            row_start = (int*)alloc((size_t)(N_NODES + 1) * 4);
    unsigned short* col       = (unsigned short*)alloc((size_t)NE_TOT * 2);
    int*            histG     = (int*)alloc((size_t)NWA * NBKT * 4);
    int*            bktTotal  = (int*)alloc((size_t)NBKT * 4);
    int*            bktBase   = (int*)alloc((size_t)(NBKT + 1) * 4);
    unsigned int*   pairs     = (unsigned int*)hB;   // alias: hB not live during CSR build

    int nbG = (N_NODES + 31) / 32;
    int nbA = (N_NODES + 3) / 4;

    // fused: binhist (blocks 0..NWA) || layer-1 GEMM (blocks NWA..NWA+nbG)
    k_hist_gemm<<<NWA + nbG, 256, 0, stream>>>(ei, histG, x, W1, attS1, attD1,
                                               h16, a_s, a_d);

    // cooperative CSR: scan + base + scatter + sort in one kernel
    {
        const int* ei_a = ei;
        int* histG_a = histG;
        int* bktTotal_a = bktTotal;
        int* bktBase_a = bktBase;
        int* row_start_a = row_start;
        unsigned int* pairs_a = pairs;
        unsigned short* col_a = col;
        void* args[] = { (void*)&ei_a, (void*)&histG_a, (void*)&bktTotal_a,
                         (void*)&bktBase_a, (void*)&row_start_a,
                         (void*)&pairs_a, (void*)&col_a };
        hipLaunchCooperativeKernel((const void*)k_csr, dim3(NWA), dim3(256),
                                   args, 0, stream);
    }

    k_agg<1><<<nbA, 256, 0, stream>>>(h16, a_s, a_d, row_start, col, b1, hB,
                                      Wout, bout, out);
    k_gemm_att<<<nbG, 256, 0, stream>>>(hB, W2, attS2, attD2, h16, a_s, a_d);
    k_agg<0><<<nbA, 256, 0, stream>>>(h16, a_s, a_d, row_start, col, b2, hB,
                                      Wout, bout, out);
}

// Round 15
// 253.883 us; speedup vs baseline: 1.6778x; 1.6778x over previous
//
#include <hip/hip_runtime.h>
#include <hip/hip_fp16.h>
#include <math.h>

#define N_NODES 50000
#define E_EDGES 1600000
#define NE_TOT  (E_EDGES + N_NODES)

// bucketed scatter geometry
#define BSH 7                                   // 128 nodes per bucket
#define NBKT ((N_NODES + 127) >> 7)             // 391 buckets
#define EPW 4096                                // edges per A-pass workgroup
#define NWA ((NE_TOT + EPW - 1) / EPW)          // 403 workgroups
#define CAP 5120                                // per-bucket region capacity
                                                // (mean 4224, sigma 65 -> 13.8σ)
#define CH 128                                  // staged edges per node chunk

// ---------------- fused: hist+reserve+scatter  ||  layer-1 GEMM ----------------

__device__ __forceinline__ void gemm_att_body(
    int bid, int t, float* Wl, float* xs,
    const float* __restrict__ X, const float* __restrict__ W,
    const float* __restrict__ attS, const float* __restrict__ attD,
    __half* __restrict__ H16, float* __restrict__ a_s, float* __restrict__ a_d) {
    int g = t >> 5, cl = t & 31, c4 = cl * 4;
    int rowbase = bid * 32;
    float4 acc[4];
    #pragma unroll
    for (int rr = 0; rr < 4; rr++) acc[rr] = make_float4(0.f, 0.f, 0.f, 0.f);

    for (int kp = 0; kp < 2; kp++) {
        __syncthreads();
        #pragma unroll
        for (int j = 0; j < 8; j++) {
            int f4 = t + 256 * j;
            int kk = f4 >> 5, cg2 = f4 & 31;
            *(float4*)&Wl[kk * 128 + cg2 * 4] =
                *(const float4*)&W[(kp * 64 + kk) * 128 + cg2 * 4];
        }
        #pragma unroll
        for (int j = 0; j < 2; j++) {
            int f4 = t + 256 * j;
            int r = f4 >> 4, k4 = f4 & 15;
            int grow = rowbase + r;
            float4 xv = make_float4(0.f, 0.f, 0.f, 0.f);
            if (grow < N_NODES) xv = *(const float4*)&X[grow * 128 + kp * 64 + k4 * 4];
            *(float4*)&xs[r * 64 + k4 * 4] = xv;
        }
        __syncthreads();
        #pragma unroll
        for (int k4 = 0; k4 < 16; k4++) {
            float4 xv[4];
            #pragma unroll
            for (int rr = 0; rr < 4; rr++)
                xv[rr] = *(float4*)&xs[(g * 4 + rr) * 64 + k4 * 4];
            #pragma unroll
            for (int kk = 0; kk < 4; kk++) {
                float4 wv = *(float4*)&Wl[(k4 * 4 + kk) * 128 + c4];
                #pragma unroll
                for (int rr = 0; rr < 4; rr++) {
                    float xc = (kk == 0) ? xv[rr].x : (kk == 1) ? xv[rr].y
                             : (kk == 2) ? xv[rr].z : xv[rr].w;
                    acc[rr].x += xc * wv.x;
                    acc[rr].y += xc * wv.y;
                    acc[rr].z += xc * wv.z;
                    acc[rr].w += xc * wv.w;
                }
            }
        }
    }

    float4 as4 = *(const float4*)&attS[c4];
    float4 ad4 = *(const float4*)&attD[c4];
    int head = cl >> 3;
    #pragma unroll
    for (int rr = 0; rr < 4; rr++) {
        int grow = rowbase + g * 4 + rr;
        float4 a = acc[rr];
        if (grow < N_NODES) {
            __half2 lo = __floats2half2_rn(a.x, a.y);
            __half2 hi = __floats2half2_rn(a.z, a.w);
            uint2 pk;
            pk.x = *(unsigned int*)&lo;
            pk.y = *(unsigned int*)&hi;
            *(uint2*)&H16[(size_t)grow * 128 + c4] = pk;
        }
        float ps = a.x * as4.x + a.y * as4.y + a.z * as4.z + a.w * as4.w;
        float pd = a.x * ad4.x + a.y * ad4.y + a.z * ad4.z + a.w * ad4.w;
        ps += __shfl_xor(ps, 1); ps += __shfl_xor(ps, 2); ps += __shfl_xor(ps, 4);
        pd += __shfl_xor(pd, 1); pd += __shfl_xor(pd, 2); pd += __shfl_xor(pd, 4);
        if ((cl & 7) == 0 && grow < N_NODES) {
            a_s[grow * 4 + head] = ps;
            a_d[grow * 4 + head] = pd;
        }
    }
}

// blocks [0,NWA): hist -> global atomic range-reserve -> scatter packed pairs
// blocks [NWA,..): layer-1 GEMM + attention logits
__global__ __launch_bounds__(256) void k_hist_scatter_gemm(
    const int* __restrict__ ei, int* __restrict__ cursor,
    unsigned int* __restrict__ pairs,
    const float* __restrict__ X, const float* __restrict__ W,
    const float* __restrict__ attS, const float* __restrict__ attD,
    __half* __restrict__ H16, float* __restrict__ a_s, float* __restrict__ a_d) {
    __shared__ __align__(16) char smem[40960];
    int t = threadIdx.x;
    if (blockIdx.x < NWA) {
        int* h    = (int*)smem;          // NBKT counts
        int* wcur = ((int*)smem) + NBKT; // NBKT absolute write cursors
        for (int i = t; i < NBKT; i += 256) h[i] = 0;
        __syncthreads();
        int base = blockIdx.x * EPW;
        #pragma unroll 4
        for (int j = 0; j < EPW / 256; j++) {
            int e = base + t + 256 * j;
            if (e < NE_TOT) {
                int d = (e < E_EDGES) ? ei[E_EDGES + e] : (e - E_EDGES);
                atomicAdd(&h[d >> BSH], 1);
            }
        }
        __syncthreads();
        for (int i = t; i < NBKT; i += 256) {
            int c = h[i];
            int rel = (c > 0) ? atomicAdd(&cursor[i], c) : 0;
            wcur[i] = i * CAP + rel;
        }
        __syncthreads();
        #pragma unroll 4
        for (int j = 0; j < EPW / 256; j++) {
            int e = base + t + 256 * j;
            if (e < NE_TOT) {
                int s, d;
                if (e < E_EDGES) { s = ei[e]; d = ei[E_EDGES + e]; }
                else             { s = d = e - E_EDGES; }
                int pos = atomicAdd(&wcur[d >> BSH], 1);
                pairs[pos] = ((unsigned int)d << 16) | (unsigned int)s;
            }
        }
    } else {
        float* Wl = (float*)smem;              // 64*128 floats = 32KB
        float* xs = (float*)(smem + 32768);    // 32*64 floats = 8KB
        gemm_att_body(blockIdx.x - NWA, t, Wl, xs, X, W, attS, attD, H16, a_s, a_d);
    }
}

// standalone GEMM (layer 2)
__global__ __launch_bounds__(256) void k_gemm_att(
    const float* __restrict__ X, const float* __restrict__ W,
    const float* __restrict__ attS, const float* __restrict__ attD,
    __half* __restrict__ H16, float* __restrict__ a_s, float* __restrict__ a_d) {
    __shared__ float Wl[64 * 128];
    __shared__ float xs[32 * 64];
    gemm_att_body(blockIdx.x, threadIdx.x, Wl, xs, X, W, attS, attD, H16, a_s, a_d);
}

// per bucket: node-level count+scan -> rbeg/rend; scatter src into col
__global__ __launch_bounds__(256) void k_bucketsort(
    const unsigned int* __restrict__ pairs, const int* __restrict__ cursor,
    int* __restrict__ rbeg, int* __restrict__ rend,
    unsigned short* __restrict__ col) {
    __shared__ int cnt[1 << BSH];
    __shared__ int sc[1 << BSH];
    __shared__ int cur[1 << BSH];
    int b = blockIdx.x, t = threadIdx.x;
    int nbeg = b << BSH;
    int ebeg = b * CAP;
    int eend = ebeg + cursor[b];
    if (t < (1 << BSH)) cnt[t] = 0;
    __syncthreads();
    for (int j = ebeg + t; j < eend; j += 256)
        atomicAdd(&cnt[(int)(pairs[j] >> 16) - nbeg], 1);
    __syncthreads();
    int v = (t < (1 << BSH)) ? cnt[t] : 0;
    if (t < (1 << BSH)) sc[t] = v;
    __syncthreads();
    for (int d = 1; d < (1 << BSH); d <<= 1) {
        int x = 0;
        if (t < (1 << BSH) && t >= d) x = sc[t - d];
        __syncthreads();
        if (t < (1 << BSH)) sc[t] += x;
        __syncthreads();
    }
    if (t < (1 << BSH)) {
        int pos = ebeg + sc[t] - v;      // exclusive within bucket region
        cur[t] = pos;
        int node = nbeg + t;
        if (node < N_NODES) { rbeg[node] = pos; rend[node] = pos + v; }
    }
    __syncthreads();
    for (int j = ebeg + t; j < eend; j += 256) {
        unsigned int p = pairs[j];
        int pos = atomicAdd(&cur[(int)(p >> 16) - nbeg], 1);
        col[pos] = (unsigned short)(p & 0xFFFFu);
    }
}

// ---------------- Attention aggregation ----------------

__device__ inline float sel4(float4 v, int i) {
    float r = v.x;
    if (i == 1) r = v.y;
    if (i == 2) r = v.z;
    if (i == 3) r = v.w;
    return r;
}

// p = exp(leaky_relu(a + b)) — no max subtraction (|logits| <~ 2, fp32-safe)
__device__ inline float4 expleaky4(float4 a, float4 b) {
    float4 e, p;
    e.x = a.x + b.x; e.x = e.x > 0.f ? e.x : 0.2f * e.x; p.x = __expf(e.x);
    e.y = a.y + b.y; e.y = e.y > 0.f ? e.y : 0.2f * e.y; p.y = __expf(e.y);
    e.z = a.z + b.z; e.z = e.z > 0.f ? e.z : 0.2f * e.z; p.z = __expf(e.z);
    e.w = a.w + b.w; e.w = e.w > 0.f ? e.w : 0.2f * e.w; p.w = __expf(e.w);
    return p;
}

#define ACC8(q, raw)                                              \
    do {                                                          \
        const __half2* hp_ = (const __half2*)&(raw);              \
        float2 f0_ = __half22float2(hp_[0]);                      \
        float2 f1_ = __half22float2(hp_[1]);                      \
        float2 f2_ = __half22float2(hp_[2]);                      \
        float2 f3_ = __half22float2(hp_[3]);                      \
        acc8[0] = fmaf((q), f0_.x, acc8[0]);                      \
        acc8[1] = fmaf((q), f0_.y, acc8[1]);                      \
        acc8[2] = fmaf((q), f1_.x, acc8[2]);                      \
        acc8[3] = fmaf((q), f1_.y, acc8[3]);                      \
        acc8[4] = fmaf((q), f2_.x, acc8[4]);                      \
        acc8[5] = fmaf((q), f2_.y, acc8[5]);                      \
        acc8[6] = fmaf((q), f3_.x, acc8[6]);                      \
        acc8[7] = fmaf((q), f3_.y, acc8[7]);                      \
    } while (0)

// R10/R13-validated geometry: 256-thread blocks = 4 waves = 4 independent nodes;
// consume: 4 edge slots x 16 channel-lanes x 8 ch/lane, 4-deep load batching.
template<int MODE>   // 1: layer-1 (ELU -> Hout fp32); 0: layer-2 (fused out-proj)
__global__ __launch_bounds__(256) void k_agg(
    const __half* __restrict__ H16, const float* __restrict__ a_s,
    const float* __restrict__ a_d, const int* __restrict__ rbeg,
    const int* __restrict__ rend,
    const unsigned short* __restrict__ col, const float* __restrict__ bias,
    float* __restrict__ Hout,
    const float* __restrict__ Wout, const float* __restrict__ bout,
    float* __restrict__ out) {
    __shared__ float4 eS[4][CH];    // staged p per wave
    __shared__ int    sS[4][CH];    // staged src per wave
    __shared__ float  WoT[(MODE == 0) ? 1024 : 1];  // transposed Wout [8][128]
    __shared__ float  boL[(MODE == 0) ? 8 : 1];

    if (MODE == 0) {
        for (int j = threadIdx.x; j < 1024; j += 256) {
            int o = j >> 7, k = j & 127;
            WoT[o * 128 + k] = Wout[k * 8 + o];
        }
        if (threadIdx.x < 8) boL[threadIdx.x] = bout[threadIdx.x];
        __syncthreads();
    }

    int wid = threadIdx.x >> 6;
    int lane = threadIdx.x & 63;
    int node = blockIdx.x * 4 + wid;
    if (node >= N_NODES) return;
    int beg = rbeg[node], end = rend[node];
    int deg = end - beg;
    float4 ad4 = *(const float4*)&a_d[node * 4];
    float4* eA = eS[wid];
    int*    srcA = sS[wid];

    // single pass: p = exp(leaky(e)), stage {src,p} (first CH), accumulate denom
    float4 s = make_float4(0.f, 0.f, 0.f, 0.f);
    for (int j = beg + lane; j < end; j += 64) {
        int src = (int)col[j];
        float4 av = *(const float4*)&a_s[src * 4];
        float4 p = expleaky4(av, ad4);
        int idx = j - beg;
        if (idx < CH) { srcA[idx] = src; eA[idx] = p; }
        s.x += p.x; s.y += p.y; s.z += p.z; s.w += p.w;
    }
    #pragma unroll
    for (int off = 32; off > 0; off >>= 1) {
        s.x += __shfl_xor(s.x, off);
        s.y += __shfl_xor(s.y, off);
        s.z += __shfl_xor(s.z, off);
        s.w += __shfl_xor(s.w, off);
    }
    float4 inv;
    inv.x = 1.f / (s.x + 1e-16f);
    inv.y = 1.f / (s.y + 1e-16f);
    inv.z = 1.f / (s.z + 1e-16f);
    inv.w = 1.f / (s.w + 1e-16f);

    // consume: 4 edge slots x 16 channel-lanes (8 fp16 ch each = 16B load);
    // 4-edge batches per slot for MLP
    int eslot = lane >> 4, cl16 = lane & 15, head = cl16 >> 2;
    const __half* hbase = H16 + cl16 * 8;
    const float* pA = (const float*)eA;
    float acc8[8];
    #pragma unroll
    for (int k = 0; k < 8; k++) acc8[k] = 0.f;

    int nst = min(deg, CH);
    int i = eslot;
    for (; i + 12 < nst; i += 16) {
        int s0 = srcA[i];
        int s1 = srcA[i + 4];
        int s2 = srcA[i + 8];
        int s3 = srcA[i + 12];
        float q0 = pA[i * 4 + head];
        float q1 = pA[(i + 4) * 4 + head];
        float q2 = pA[(i + 8) * 4 + head];
        float q3 = pA[(i + 12) * 4 + head];
        float4 r0 = *(const float4*)(hbase + (size_t)s0 * 128);
        float4 r1 = *(const float4*)(hbase + (size_t)s1 * 128);
        float4 r2 = *(const float4*)(hbase + (size_t)s2 * 128);
        float4 r3 = *(const float4*)(hbase + (size_t)s3 * 128);
        ACC8(q0, r0);
        ACC8(q1, r1);
        ACC8(q2, r2);
        ACC8(q3, r3);
    }
    for (; i < nst; i += 4) {
        int src = srcA[i];
        float p = pA[i * 4 + head];
        float4 raw = *(const float4*)(hbase + (size_t)src * 128);
        ACC8(p, raw);
    }
    // overflow chunks (deg > CH, rare): restage then consume
    for (int cb = beg + CH; cb < end; cb += CH) {
        int cnt = min(end - cb, CH);
        for (int idx = lane; idx < cnt; idx += 64) {
            int src = (int)col[cb + idx];
            float4 av = *(const float4*)&a_s[src * 4];
            float4 p = expleaky4(av, ad4);
            srcA[idx] = src; eA[idx] = p;
        }
        for (int ii = eslot; ii < cnt; ii += 4) {
            int src = srcA[ii];
            float p = pA[ii * 4 + head];
            float4 raw = *(const float4*)(hbase + (size_t)src * 128);
            ACC8(p, raw);
        }
    }

    #pragma unroll
    for (int k = 0; k < 8; k++) {
        acc8[k] += __shfl_xor(acc8[k], 16);
        acc8[k] += __shfl_xor(acc8[k], 32);
    }

    float ih = sel4(inv, head);
    if (MODE == 1) {
        if (eslot == 0) {
            const float* bp = &bias[cl16 * 8];
            float o[8];
            #pragma unroll
            for (int k = 0; k < 8; k++) {
                o[k] = acc8[k] * ih + bp[k];
                o[k] = o[k] > 0.f ? o[k] : expm1f(o[k]);
            }
            float* op = &Hout[(size_t)node * 128 + cl16 * 8];
            *(float4*)&op[0] = make_float4(o[0], o[1], o[2], o[3]);
            *(float4*)&op[4] = make_float4(o[4], o[5], o[6], o[7]);
        }
    } else {
        // fused output projection: h2 = acc*ih + b2 (all lanes hold it),
        // each eslot computes 2 of the 8 outputs
        const float* bp = &bias[cl16 * 8];
        float4 oa, ob;
        oa.x = acc8[0] * ih + bp[0]; oa.y = acc8[1] * ih + bp[1];
        oa.z = acc8[2] * ih + bp[2]; oa.w = acc8[3] * ih + bp[3];
        ob.x = acc8[4] * ih + bp[4]; ob.y = acc8[5] * ih + bp[5];
        ob.z = acc8[6] * ih + bp[6]; ob.w = acc8[7] * ih + bp[7];
        int o0 = eslot * 2;
        float p0 = 0.f, p1 = 0.f;
        {
            float4 wa = *(float4*)&WoT[o0 * 128 + cl16 * 8];
            float4 wb = *(float4*)&WoT[o0 * 128 + cl16 * 8 + 4];
            p0 = oa.x * wa.x + oa.y * wa.y + oa.z * wa.z + oa.w * wa.w
               + ob.x * wb.x + ob.y * wb.y + ob.z * wb.z + ob.w * wb.w;
            float4 wc = *(float4*)&WoT[(o0 + 1) * 128 + cl16 * 8];
            float4 wd = *(float4*)&WoT[(o0 + 1) * 128 + cl16 * 8 + 4];
            p1 = oa.x * wc.x + oa.y * wc.y + oa.z * wc.z + oa.w * wc.w
               + ob.x * wd.x + ob.y * wd.y + ob.z * wd.z + ob.w * wd.w;
        }
        #pragma unroll
        for (int d = 1; d <= 8; d <<= 1) {
            p0 += __shfl_xor(p0, d);
            p1 += __shfl_xor(p1, d);
        }
        if (cl16 == 0) {
            float2 ov = make_float2(p0 + boL[o0], p1 + boL[o0 + 1]);
            *(float2*)&out[(size_t)node * 8 + o0] = ov;
        }
    }
}

// ---------------- launch ----------------

extern "C" void kernel_launch(void* const* d_in, const int* in_sizes, int n_in,
                              void* d_out, int out_size, void* d_ws, size_t ws_size,
                              hipStream_t stream) {
    const float* x     = (const float*)d_in[0];
    const int*   ei    = (const int*)d_in[1];
    const float* W1    = (const float*)d_in[2];
    const float* attS1 = (const float*)d_in[3];
    const float* attD1 = (const float*)d_in[4];
    const float* b1    = (const float*)d_in[5];
    const float* W2    = (const float*)d_in[6];
    const float* attS2 = (const float*)d_in[7];
    const float* attD2 = (const float*)d_in[8];
    const float* b2    = (const float*)d_in[9];
    const float* Wout  = (const float*)d_in[10];
    const float* bout  = (const float*)d_in[11];
    float* out = (float*)d_out;

    char* ws = (char*)d_ws;
    size_t off = 0;
    auto alloc = [&](size_t bytes) -> void* {
        void* p = ws + off;
        off += (bytes + 255) & ~(size_t)255;
        return p;
    };
    float*          hB     = (float*)alloc((size_t)N_NODES * 128 * 4);
    __half*         h16    = (__half*)alloc((size_t)N_NODES * 128 * 2);
    float*          a_s    = (float*)alloc((size_t)N_NODES * 4 * 4);
    float*          a_d    = (float*)alloc((size_t)N_NODES * 4 * 4);
    int*            rbeg   = (int*)alloc((size_t)N_NODES * 4);
    int*            rend   = (int*)alloc((size_t)N_NODES * 4);
    unsigned short* col    = (unsigned short*)alloc((size_t)NBKT * CAP * 2);
    int*            cursor = (int*)alloc((size_t)NBKT * 4);
    unsigned int*   pairs  = (unsigned int*)hB;   // 391*5120*4 = 8.0MB < 25.6MB
                                                  // (hB not live during CSR build)

    int nbG = (N_NODES + 31) / 32;
    int nbA = (N_NODES + 3) / 4;

    hipMemsetAsync(cursor, 0, (size_t)NBKT * 4, stream);
    // fused: hist+reserve+scatter (blocks 0..NWA) || layer-1 GEMM (rest)
    k_hist_scatter_gemm<<<NWA + nbG, 256, 0, stream>>>(
        ei, cursor, pairs, x, W1, attS1, attD1, h16, a_s, a_d);
    k_bucketsort<<<NBKT, 256, 0, stream>>>(pairs, cursor, rbeg, rend, col);

    k_agg<1><<<nbA, 256, 0, stream>>>(h16, a_s, a_d, rbeg, rend, col, b1, hB,
                                      Wout, bout, out);
    k_gemm_att<<<nbG, 256, 0, stream>>>(hB, W2, attS2, attD2, h16, a_s, a_d);
    k_agg<0><<<nbA, 256, 0, stream>>>(h16, a_s, a_d, rbeg, rend, col, b2, hB,
                                      Wout, bout, out);
}

// Round 16
// 236.348 us; speedup vs baseline: 1.8023x; 1.0742x over previous
//
#include <hip/hip_runtime.h>
#include <hip/hip_fp16.h>
#include <math.h>

#define N_NODES 50000
#define E_EDGES 1600000
#define NE_TOT  (E_EDGES + N_NODES)

// bucketed scatter geometry
#define BSH 7                                   // 128 nodes per bucket
#define NBKT ((N_NODES + 127) >> 7)             // 391 buckets
#define EPW 4096                                // edges per A-pass workgroup
#define NWA ((NE_TOT + EPW - 1) / EPW)          // 403 workgroups
#define CAP 5120                                // per-bucket region capacity
#define CH 128                                  // staged edges per node chunk

// MFMA GEMM geometry: 64 rows/block, fp16 operands in LDS
#define GROWS 64
#define XH_STRIDE 136                           // halves; pad for A-read banks
#define WR_STRIDE 130                           // halves; pad -> B-gather 2-way free
#define XH_BYTES (GROWS * XH_STRIDE * 2)        // 17408
#define WR_BYTES (128 * WR_STRIDE * 2)          // 33280
#define GEMM_LDS (XH_BYTES + WR_BYTES)          // 50688

typedef _Float16 f16x8 __attribute__((ext_vector_type(8)));
typedef float    f32x4 __attribute__((ext_vector_type(4)));

// ---------------- MFMA GEMM (h = X @ W, fp16 in, fp32 acc) + attention logits ----

__device__ __forceinline__ void gemm_att_body(
    int bid, int t, _Float16* xh, _Float16* wr,
    const float* __restrict__ X, const float* __restrict__ W,
    const float* __restrict__ attS, const float* __restrict__ attD,
    __half* __restrict__ H16, float* __restrict__ a_s, float* __restrict__ a_d) {
    int rowbase = bid * GROWS;

    // stage X[64][128] -> xh fp16
    #pragma unroll
    for (int j = 0; j < 8; j++) {
        int f4 = t + 256 * j;            // 0..2047
        int r  = f4 >> 5;                // 0..63
        int k4 = (f4 & 31) * 4;
        int grow = rowbase + r;
        float4 xv = make_float4(0.f, 0.f, 0.f, 0.f);
        if (grow < N_NODES) xv = *(const float4*)&X[(size_t)grow * 128 + k4];
        __half2 lo = __floats2half2_rn(xv.x, xv.y);
        __half2 hi = __floats2half2_rn(xv.z, xv.w);
        *(__half2*)&xh[r * XH_STRIDE + k4]     = lo;
        *(__half2*)&xh[r * XH_STRIDE + k4 + 2] = hi;
    }
    // stage W[128][128] -> wr fp16 (row-major, padded stride)
    #pragma unroll
    for (int j = 0; j < 16; j++) {
        int f4 = t + 256 * j;            // 0..4095
        int k  = f4 >> 5;                // 0..127
        int c0 = (f4 & 31) * 4;
        float4 wv = *(const float4*)&W[k * 128 + c0];
        __half2 lo = __floats2half2_rn(wv.x, wv.y);
        __half2 hi = __floats2half2_rn(wv.z, wv.w);
        *(__half2*)&wr[k * WR_STRIDE + c0]     = lo;
        *(__half2*)&wr[k * WR_STRIDE + c0 + 2] = hi;
    }
    __syncthreads();

    int lane = t & 63;
    int w    = t >> 6;        // wave == head (cols 32w..32w+31)
    int lrow = lane & 15;     // A-row / B-col / D-col
    int g    = lane >> 4;     // k-group

    // A fragments: [rt][ks], reused across both col-tiles
    f16x8 afr[4][4];
    #pragma unroll
    for (int rt = 0; rt < 4; rt++)
        #pragma unroll
        for (int ks = 0; ks < 4; ks++)
            afr[rt][ks] = *(f16x8*)&xh[(rt * 16 + lrow) * XH_STRIDE + ks * 32 + g * 8];

    f32x4 acc[2][4];
    #pragma unroll
    for (int hf = 0; hf < 2; hf++)
        #pragma unroll
        for (int rt = 0; rt < 4; rt++)
            acc[hf][rt] = (f32x4){0.f, 0.f, 0.f, 0.f};

    #pragma unroll
    for (int hf = 0; hf < 2; hf++) {
        int c = (w * 2 + hf) * 16 + lrow;
        #pragma unroll
        for (int ks = 0; ks < 4; ks++) {
            f16x8 bfr;
            #pragma unroll
            for (int j = 0; j < 8; j++)
                bfr[j] = wr[(ks * 32 + g * 8 + j) * WR_STRIDE + c];
            #pragma unroll
            for (int rt = 0; rt < 4; rt++)
                acc[hf][rt] = __builtin_amdgcn_mfma_f32_16x16x32_f16(
                    afr[rt][ks], bfr, acc[hf][rt], 0, 0, 0);
        }
    }

    // epilogue: h16 store + per-head logit partials
    float ps[4][4], pd[4][4];
    #pragma unroll
    for (int rt = 0; rt < 4; rt++)
        #pragma unroll
        for (int r = 0; r < 4; r++) { ps[rt][r] = 0.f; pd[rt][r] = 0.f; }

    #pragma unroll
    for (int hf = 0; hf < 2; hf++) {
        int ch = (w * 2 + hf) * 16 + lrow;
        float aS = attS[ch], aD = attD[ch];
        #pragma unroll
        for (int rt = 0; rt < 4; rt++) {
            #pragma unroll
            for (int r = 0; r < 4; r++) {
                float v = acc[hf][rt][r];
                int grow = rowbase + rt * 16 + g * 4 + r;
                if (grow < N_NODES) H16[(size_t)grow * 128 + ch] = __float2half(v);
                ps[rt][r] = fmaf(v, aS, ps[rt][r]);
                pd[rt][r] = fmaf(v, aD, pd[rt][r]);
            }
        }
    }
    // reduce over the 16 col-lanes (lane bits 0..3)
    #pragma unroll
    for (int rt = 0; rt < 4; rt++)
        #pragma unroll
        for (int r = 0; r < 4; r++) {
            #pragma unroll
            for (int d = 1; d <= 8; d <<= 1) {
                ps[rt][r] += __shfl_xor(ps[rt][r], d);
                pd[rt][r] += __shfl_xor(pd[rt][r], d);
            }
        }
    if (lrow == 0) {
        #pragma unroll
        for (int rt = 0; rt < 4; rt++)
            #pragma unroll
            for (int r = 0; r < 4; r++) {
                int grow = rowbase + rt * 16 + g * 4 + r;
                if (grow < N_NODES) {
                    a_s[grow * 4 + w] = ps[rt][r];
                    a_d[grow * 4 + w] = pd[rt][r];
                }
            }
    }
}

// blocks [0,NWA): hist -> atomic range-reserve -> scatter packed pairs
// blocks [NWA,..): layer-1 MFMA GEMM + attention logits
__global__ __launch_bounds__(256) void k_hist_scatter_gemm(
    const int* __restrict__ ei, int* __restrict__ cursor,
    unsigned int* __restrict__ pairs,
    const float* __restrict__ X, const float* __restrict__ W,
    const float* __restrict__ attS, const float* __restrict__ attD,
    __half* __restrict__ H16, float* __restrict__ a_s, float* __restrict__ a_d) {
    __shared__ __align__(16) char smem[GEMM_LDS];
    int t = threadIdx.x;
    if (blockIdx.x < NWA) {
        int* h    = (int*)smem;
        int* wcur = ((int*)smem) + NBKT;
        for (int i = t; i < NBKT; i += 256) h[i] = 0;
        __syncthreads();
        int base = blockIdx.x * EPW;
        #pragma unroll 4
        for (int j = 0; j < EPW / 256; j++) {
            int e = base + t + 256 * j;
            if (e < NE_TOT) {
                int d = (e < E_EDGES) ? ei[E_EDGES + e] : (e - E_EDGES);
                atomicAdd(&h[d >> BSH], 1);
            }
        }
        __syncthreads();
        for (int i = t; i < NBKT; i += 256) {
            int c = h[i];
            int rel = (c > 0) ? atomicAdd(&cursor[i], c) : 0;
            wcur[i] = i * CAP + rel;
        }
        __syncthreads();
        #pragma unroll 4
        for (int j = 0; j < EPW / 256; j++) {
            int e = base + t + 256 * j;
            if (e < NE_TOT) {
                int s, d;
                if (e < E_EDGES) { s = ei[e]; d = ei[E_EDGES + e]; }
                else             { s = d = e - E_EDGES; }
                int pos = atomicAdd(&wcur[d >> BSH], 1);
                pairs[pos] = ((unsigned int)d << 16) | (unsigned int)s;
            }
        }
    } else {
        _Float16* xh = (_Float16*)smem;
        _Float16* wr = (_Float16*)(smem + XH_BYTES);
        gemm_att_body(blockIdx.x - NWA, t, xh, wr, X, W, attS, attD, H16, a_s, a_d);
    }
}

// standalone GEMM (layer 2)
__global__ __launch_bounds__(256) void k_gemm_att(
    const float* __restrict__ X, const float* __restrict__ W,
    const float* __restrict__ attS, const float* __restrict__ attD,
    __half* __restrict__ H16, float* __restrict__ a_s, float* __restrict__ a_d) {
    __shared__ __align__(16) char smem[GEMM_LDS];
    _Float16* xh = (_Float16*)smem;
    _Float16* wr = (_Float16*)(smem + XH_BYTES);
    gemm_att_body(blockIdx.x, threadIdx.x, xh, wr, X, W, attS, attD, H16, a_s, a_d);
}

// per bucket: node-level count+scan -> rbeg/rend; scatter src into col
__global__ __launch_bounds__(256) void k_bucketsort(
    const unsigned int* __restrict__ pairs, const int* __restrict__ cursor,
    int* __restrict__ rbeg, int* __restrict__ rend,
    unsigned short* __restrict__ col) {
    __shared__ int cnt[1 << BSH];
    __shared__ int sc[1 << BSH];
    __shared__ int cur[1 << BSH];
    int b = blockIdx.x, t = threadIdx.x;
    int nbeg = b << BSH;
    int ebeg = b * CAP;
    int eend = ebeg + cursor[b];
    if (t < (1 << BSH)) cnt[t] = 0;
    __syncthreads();
    for (int j = ebeg + t; j < eend; j += 256)
        atomicAdd(&cnt[(int)(pairs[j] >> 16) - nbeg], 1);
    __syncthreads();
    int v = (t < (1 << BSH)) ? cnt[t] : 0;
    if (t < (1 << BSH)) sc[t] = v;
    __syncthreads();
    for (int d = 1; d < (1 << BSH); d <<= 1) {
        int x = 0;
        if (t < (1 << BSH) && t >= d) x = sc[t - d];
        __syncthreads();
        if (t < (1 << BSH)) sc[t] += x;
        __syncthreads();
    }
    if (t < (1 << BSH)) {
        int pos = ebeg + sc[t] - v;      // exclusive within bucket region
        cur[t] = pos;
        int node = nbeg + t;
        if (node < N_NODES) { rbeg[node] = pos; rend[node] = pos + v; }
    }
    __syncthreads();
    for (int j = ebeg + t; j < eend; j += 256) {
        unsigned int p = pairs[j];
        int pos = atomicAdd(&cur[(int)(p >> 16) - nbeg], 1);
        col[pos] = (unsigned short)(p & 0xFFFFu);
    }
}

// ---------------- Attention aggregation (R10/R13-validated geometry) ----------------

__device__ inline float sel4(float4 v, int i) {
    float r = v.x;
    if (i == 1) r = v.y;
    if (i == 2) r = v.z;
    if (i == 3) r = v.w;
    return r;
}

// p = exp(leaky_relu(a + b)) — no max subtraction (|logits| <~ 2, fp32-safe)
__device__ inline float4 expleaky4(float4 a, float4 b) {
    float4 e, p;
    e.x = a.x + b.x; e.x = e.x > 0.f ? e.x : 0.2f * e.x; p.x = __expf(e.x);
    e.y = a.y + b.y; e.y = e.y > 0.f ? e.y : 0.2f * e.y; p.y = __expf(e.y);
    e.z = a.z + b.z; e.z = e.z > 0.f ? e.z : 0.2f * e.z; p.z = __expf(e.z);
    e.w = a.w + b.w; e.w = e.w > 0.f ? e.w : 0.2f * e.w; p.w = __expf(e.w);
    return p;
}

#define ACC8(q, raw)                                              \
    do {                                                          \
        const __half2* hp_ = (const __half2*)&(raw);              \
        float2 f0_ = __half22float2(hp_[0]);                      \
        float2 f1_ = __half22float2(hp_[1]);                      \
        float2 f2_ = __half22float2(hp_[2]);                      \
        float2 f3_ = __half22float2(hp_[3]);                      \
        acc8[0] = fmaf((q), f0_.x, acc8[0]);                      \
        acc8[1] = fmaf((q), f0_.y, acc8[1]);                      \
        acc8[2] = fmaf((q), f1_.x, acc8[2]);                      \
        acc8[3] = fmaf((q), f1_.y, acc8[3]);                      \
        acc8[4] = fmaf((q), f2_.x, acc8[4]);                      \
        acc8[5] = fmaf((q), f2_.y, acc8[5]);                      \
        acc8[6] = fmaf((q), f3_.x, acc8[6]);                      \
        acc8[7] = fmaf((q), f3_.y, acc8[7]);                      \
    } while (0)

template<int MODE>   // 1: layer-1 (ELU -> Hout fp32); 0: layer-2 (fused out-proj)
__global__ __launch_bounds__(256) void k_agg(
    const __half* __restrict__ H16, const float* __restrict__ a_s,
    const float* __restrict__ a_d, const int* __restrict__ rbeg,
    const int* __restrict__ rend,
    const unsigned short* __restrict__ col, const float* __restrict__ bias,
    float* __restrict__ Hout,
    const float* __restrict__ Wout, const float* __restrict__ bout,
    float* __restrict__ out) {
    __shared__ float4 eS[4][CH];    // staged p per wave
    __shared__ int    sS[4][CH];    // staged src per wave
    __shared__ float  WoT[(MODE == 0) ? 1024 : 1];  // transposed Wout [8][128]
    __shared__ float  boL[(MODE == 0) ? 8 : 1];

    if (MODE == 0) {
        for (int j = threadIdx.x; j < 1024; j += 256) {
            int o = j >> 7, k = j & 127;
            WoT[o * 128 + k] = Wout[k * 8 + o];
        }
        if (threadIdx.x < 8) boL[threadIdx.x] = bout[threadIdx.x];
        __syncthreads();
    }

    int wid = threadIdx.x >> 6;
    int lane = threadIdx.x & 63;
    int node = blockIdx.x * 4 + wid;
    if (node >= N_NODES) return;
    int beg = rbeg[node], end = rend[node];
    int deg = end - beg;
    float4 ad4 = *(const float4*)&a_d[node * 4];
    float4* eA = eS[wid];
    int*    srcA = sS[wid];

    float4 s = make_float4(0.f, 0.f, 0.f, 0.f);
    for (int j = beg + lane; j < end; j += 64) {
        int src = (int)col[j];
        float4 av = *(const float4*)&a_s[src * 4];
        float4 p = expleaky4(av, ad4);
        int idx = j - beg;
        if (idx < CH) { srcA[idx] = src; eA[idx] = p; }
        s.x += p.x; s.y += p.y; s.z += p.z; s.w += p.w;
    }
    #pragma unroll
    for (int off = 32; off > 0; off >>= 1) {
        s.x += __shfl_xor(s.x, off);
        s.y += __shfl_xor(s.y, off);
        s.z += __shfl_xor(s.z, off);
        s.w += __shfl_xor(s.w, off);
    }
    float4 inv;
    inv.x = 1.f / (s.x + 1e-16f);
    inv.y = 1.f / (s.y + 1e-16f);
    inv.z = 1.f / (s.z + 1e-16f);
    inv.w = 1.f / (s.w + 1e-16f);

    int eslot = lane >> 4, cl16 = lane & 15, head = cl16 >> 2;
    const __half* hbase = H16 + cl16 * 8;
    const float* pA = (const float*)eA;
    float acc8[8];
    #pragma unroll
    for (int k = 0; k < 8; k++) acc8[k] = 0.f;

    int nst = min(deg, CH);
    int i = eslot;
    for (; i + 12 < nst; i += 16) {
        int s0 = srcA[i];
        int s1 = srcA[i + 4];
        int s2 = srcA[i + 8];
        int s3 = srcA[i + 12];
        float q0 = pA[i * 4 + head];
        float q1 = pA[(i + 4) * 4 + head];
        float q2 = pA[(i + 8) * 4 + head];
        float q3 = pA[(i + 12) * 4 + head];
        float4 r0 = *(const float4*)(hbase + (size_t)s0 * 128);
        float4 r1 = *(const float4*)(hbase + (size_t)s1 * 128);
        float4 r2 = *(const float4*)(hbase + (size_t)s2 * 128);
        float4 r3 = *(const float4*)(hbase + (size_t)s3 * 128);
        ACC8(q0, r0);
        ACC8(q1, r1);
        ACC8(q2, r2);
        ACC8(q3, r3);
    }
    for (; i < nst; i += 4) {
        int src = srcA[i];
        float p = pA[i * 4 + head];
        float4 raw = *(const float4*)(hbase + (size_t)src * 128);
        ACC8(p, raw);
    }
    for (int cb = beg + CH; cb < end; cb += CH) {
        int cnt = min(end - cb, CH);
        for (int idx = lane; idx < cnt; idx += 64) {
            int src = (int)col[cb + idx];
            float4 av = *(const float4*)&a_s[src * 4];
            float4 p = expleaky4(av, ad4);
            srcA[idx] = src; eA[idx] = p;
        }
        for (int ii = eslot; ii < cnt; ii += 4) {
            int src = srcA[ii];
            float p = pA[ii * 4 + head];
            float4 raw = *(const float4*)(hbase + (size_t)src * 128);
            ACC8(p, raw);
        }
    }

    #pragma unroll
    for (int k = 0; k < 8; k++) {
        acc8[k] += __shfl_xor(acc8[k], 16);
        acc8[k] += __shfl_xor(acc8[k], 32);
    }

    float ih = sel4(inv, head);
    if (MODE == 1) {
        if (eslot == 0) {
            const float* bp = &bias[cl16 * 8];
            float o[8];
            #pragma unroll
            for (int k = 0; k < 8; k++) {
                o[k] = acc8[k] * ih + bp[k];
                o[k] = o[k] > 0.f ? o[k] : expm1f(o[k]);
            }
            float* op = &Hout[(size_t)node * 128 + cl16 * 8];
            *(float4*)&op[0] = make_float4(o[0], o[1], o[2], o[3]);
            *(float4*)&op[4] = make_float4(o[4], o[5], o[6], o[7]);
        }
    } else {
        const float* bp = &bias[cl16 * 8];
        float4 oa, ob;
        oa.x = acc8[0] * ih + bp[0]; oa.y = acc8[1] * ih + bp[1];
        oa.z = acc8[2] * ih + bp[2]; oa.w = acc8[3] * ih + bp[3];
        ob.x = acc8[4] * ih + bp[4]; ob.y = acc8[5] * ih + bp[5];
        ob.z = acc8[6] * ih + bp[6]; ob.w = acc8[7] * ih + bp[7];
        int o0 = eslot * 2;
        float p0 = 0.f, p1 = 0.f;
        {
            float4 wa = *(float4*)&WoT[o0 * 128 + cl16 * 8];
            float4 wb = *(float4*)&WoT[o0 * 128 + cl16 * 8 + 4];
            p0 = oa.x * wa.x + oa.y * wa.y + oa.z * wa.z + oa.w * wa.w
               + ob.x * wb.x + ob.y * wb.y + ob.z * wb.z + ob.w * wb.w;
            float4 wc = *(float4*)&WoT[(o0 + 1) * 128 + cl16 * 8];
            float4 wd = *(float4*)&WoT[(o0 + 1) * 128 + cl16 * 8 + 4];
            p1 = oa.x * wc.x + oa.y * wc.y + oa.z * wc.z + oa.w * wc.w
               + ob.x * wd.x + ob.y * wd.y + ob.z * wd.z + ob.w * wd.w;
        }
        #pragma unroll
        for (int d = 1; d <= 8; d <<= 1) {
            p0 += __shfl_xor(p0, d);
            p1 += __shfl_xor(p1, d);
        }
        if (cl16 == 0) {
            float2 ov = make_float2(p0 + boL[o0], p1 + boL[o0 + 1]);
            *(float2*)&out[(size_t)node * 8 + o0] = ov;
        }
    }
}

// ---------------- launch ----------------

extern "C" void kernel_launch(void* const* d_in, const int* in_sizes, int n_in,
                              void* d_out, int out_size, void* d_ws, size_t ws_size,
                              hipStream_t stream) {
    const float* x     = (const float*)d_in[0];
    const int*   ei    = (const int*)d_in[1];
    const float* W1    = (const float*)d_in[2];
    const float* attS1 = (const float*)d_in[3];
    const float* attD1 = (const float*)d_in[4];
    const float* b1    = (const float*)d_in[5];
    const float* W2    = (const float*)d_in[6];
    const float* attS2 = (const float*)d_in[7];
    const float* attD2 = (const float*)d_in[8];
    const float* b2    = (const float*)d_in[9];
    const float* Wout  = (const float*)d_in[10];
    const float* bout  = (const float*)d_in[11];
    float* out = (float*)d_out;

    char* ws = (char*)d_ws;
    size_t off = 0;
    auto alloc = [&](size_t bytes) -> void* {
        void* p = ws + off;
        off += (bytes + 255) & ~(size_t)255;
        return p;
    };
    float*          hB     = (float*)alloc((size_t)N_NODES * 128 * 4);
    __half*         h16    = (__half*)alloc((size_t)N_NODES * 128 * 2);
    float*          a_s    = (float*)alloc((size_t)N_NODES * 4 * 4);
    float*          a_d    = (float*)alloc((size_t)N_NODES * 4 * 4);
    int*            rbeg   = (int*)alloc((size_t)N_NODES * 4);
    int*            rend   = (int*)alloc((size_t)N_NODES * 4);
    unsigned short* col    = (unsigned short*)alloc((size_t)NBKT * CAP * 2);
    int*            cursor = (int*)alloc((size_t)NBKT * 4);
    unsigned int*   pairs  = (unsigned int*)hB;   // 8.0MB < 25.6MB, hB not yet live

    int nbG = (N_NODES + GROWS - 1) / GROWS;   // 782
    int nbA = (N_NODES + 3) / 4;

    hipMemsetAsync(cursor, 0, (size_t)NBKT * 4, stream);
    k_hist_scatter_gemm<<<NWA + nbG, 256, 0, stream>>>(
        ei, cursor, pairs, x, W1, attS1, attD1, h16, a_s, a_d);
    k_bucketsort<<<NBKT, 256, 0, stream>>>(pairs, cursor, rbeg, rend, col);

    k_agg<1><<<nbA, 256, 0, stream>>>(h16, a_s, a_d, rbeg, rend, col, b1, hB,
                                      Wout, bout, out);
    k_gemm_att<<<nbG, 256, 0, stream>>>(hB, W2, attS2, attD2, h16, a_s, a_d);
    k_agg<0><<<nbA, 256, 0, stream>>>(h16, a_s, a_d, rbeg, rend, col, b2, hB,
                                      Wout, bout, out);
}